// Round 2
// baseline (1643.934 us; speedup 1.0000x reference)
//
#include <hip/hip_runtime.h>
#include <math.h>

#define N_ROWS 131072
#define HID 128
#define NCOEF 8
#define KPROTO 256

// ---------------------------------------------------------------------------
// One KAN layer as GEMM (64 x 1152) @ (1152 x 128) per block.
// A (activations: silu(x) | b-spline bases) built on the fly from t[][] (LDS).
// B (weights: base_w | spline_w*scaler) staged transposed per 32-wide K chunk.
// Micro-tile: 256 threads, each 4 rows x 8 cols.
// Caller must barrier after last write to t before calling; function ends
// with __syncthreads() (loop tail), so caller may immediately rewrite t.
// ---------------------------------------------------------------------------
__device__ __forceinline__ void layer_pass(
    float (&t)[64][132], float (&As)[32][68], float (&Bs)[32][132],
    const float* __restrict__ bw, const float* __restrict__ sw,
    const float* __restrict__ sc, int tid, float c[4][8])
{
    const int ty = tid >> 4;   // 0..15 -> rows ty*4
    const int tx = tid & 15;   // 0..15 -> cols tx*8

    #pragma unroll
    for (int i = 0; i < 4; ++i)
        #pragma unroll
        for (int j = 0; j < 8; ++j) c[i][j] = 0.0f;

    // 36 K-chunks: 0..3 base path (k=0..127), 4..35 spline path (k=128..1151)
    for (int ch = 0; ch < 36; ++ch) {
        // ---- build A chunk [kk][m] ----
        if (ch < 4) {
            const int k0 = ch * 32;
            const int m  = tid >> 2;
            const int kq = tid & 3;
            #pragma unroll
            for (int j = 0; j < 8; ++j) {
                int kk = kq * 8 + j;
                float x = t[m][k0 + kk];
                As[kk][m] = x / (1.0f + expf(-x));     // silu
            }
        } else {
            const int i0 = (ch - 4) * 4;               // first feature of chunk
            const int m  = tid >> 2;                   // 0..63
            const int fi = tid & 3;                    // feature within chunk
            float x = t[m][i0 + fi];
            // cardinal cubic B-spline, uniform knots g[j] = (j-3)*0.4 - 1
            float s  = (x + 2.2f) * 2.5f;
            float tf = floorf(s);
            int   tt = (int)tf;
            bool valid = (tt >= 0) && (tt <= 10);
            float kt = (float)(tt - 3) * 0.4f - 1.0f;
            float u  = (x - kt) * 2.5f;
            float u2 = u * u, u3 = u2 * u;
            float om = 1.0f - u;
            float b3 = u3 * (1.0f / 6.0f);                                  // slot tt
            float b2 = (-3.0f * u3 + 3.0f * u2 + 3.0f * u + 1.0f) * (1.0f / 6.0f); // tt-1
            float b1 = (3.0f * u3 - 6.0f * u2 + 4.0f) * (1.0f / 6.0f);      // tt-2
            float b0 = om * om * om * (1.0f / 6.0f);                        // tt-3
            #pragma unroll
            for (int cix = 0; cix < 8; ++cix) {
                int d = tt - cix;
                float v = 0.0f;
                v = (d == 0) ? b3 : v;
                v = (d == 1) ? b2 : v;
                v = (d == 2) ? b1 : v;
                v = (d == 3) ? b0 : v;
                As[fi * 8 + cix][m] = valid ? v : 0.0f;
            }
        }
        // ---- build B chunk [kk][o] ----
        if (ch < 4) {
            const int k0   = ch * 32;
            const int o    = tid >> 1;
            const int half = tid & 1;
            const float4* src = (const float4*)(bw + (size_t)o * HID + k0 + half * 16);
            #pragma unroll
            for (int j = 0; j < 4; ++j) {
                float4 v = src[j];
                int kk = half * 16 + j * 4;
                Bs[kk][o] = v.x; Bs[kk + 1][o] = v.y; Bs[kk + 2][o] = v.z; Bs[kk + 3][o] = v.w;
            }
        } else {
            const int i0   = (ch - 4) * 4;
            const int o    = tid >> 1;
            const int half = tid & 1;
            float sc0 = sc[(size_t)o * HID + i0 + half * 2];
            float sc1 = sc[(size_t)o * HID + i0 + half * 2 + 1];
            const float4* src = (const float4*)(sw + ((size_t)o * HID + i0) * NCOEF + half * 16);
            #pragma unroll
            for (int j = 0; j < 4; ++j) {
                float4 v = src[j];
                float scv = (j < 2) ? sc0 : sc1;
                int kk = half * 16 + j * 4;
                Bs[kk][o] = v.x * scv; Bs[kk + 1][o] = v.y * scv;
                Bs[kk + 2][o] = v.z * scv; Bs[kk + 3][o] = v.w * scv;
            }
        }
        __syncthreads();

        // ---- GEMM on the chunk ----
        #pragma unroll
        for (int kk = 0; kk < 32; ++kk) {
            float4 a  = *(const float4*)&As[kk][ty * 4];
            float4 b0 = *(const float4*)&Bs[kk][tx * 8];
            float4 b1 = *(const float4*)&Bs[kk][tx * 8 + 4];
            float av[4] = { a.x, a.y, a.z, a.w };
            float bv[8] = { b0.x, b0.y, b0.z, b0.w, b1.x, b1.y, b1.z, b1.w };
            #pragma unroll
            for (int i = 0; i < 4; ++i)
                #pragma unroll
                for (int j = 0; j < 8; ++j)
                    c[i][j] = fmaf(av[i], bv[j], c[i][j]);
        }
        __syncthreads();
    }
}

// ---------------------------------------------------------------------------
// Fully fused: x -> KANLinear1 -> KANLinear2 -> emb (global write) ->
// cosine-sim argmax vs 256 prototypes. d_out is WRITE-ONLY.
// ---------------------------------------------------------------------------
__global__ __launch_bounds__(256, 2)
void kan_fused(const float* __restrict__ x,       // (N,128)
               const float* __restrict__ protos,  // (256,128)
               const float* __restrict__ bw1, const float* __restrict__ sw1,
               const float* __restrict__ sc1,
               const float* __restrict__ bw2, const float* __restrict__ sw2,
               const float* __restrict__ sc2,
               float* __restrict__ emb_out,       // (N,128)
               float* __restrict__ assign_out)    // (N,) as float
{
    __shared__ float t[64][132];    // x tile -> h tile -> emb tile
    __shared__ float As[32][68];    // A chunk [kk][m]
    __shared__ float Bs[32][132];   // B chunk [kk][o]; reused for proto chunks
    __shared__ float rnp[KPROTO];   // 1/max(|proto|, eps)

    const int tid = threadIdx.x;
    const int brow = blockIdx.x * 64;

    // ---- proto norms (one proto per thread) ----
    {
        const float4* pr = (const float4*)(protos + (size_t)tid * HID);
        float s = 0.0f;
        #pragma unroll
        for (int j = 0; j < 32; ++j) {
            float4 v = pr[j];
            s += v.x * v.x + v.y * v.y + v.z * v.z + v.w * v.w;
        }
        rnp[tid] = 1.0f / fmaxf(sqrtf(s), 1e-8f);
    }

    // ---- stage x tile ----
    {
        const int m  = tid >> 2;
        const int kq = tid & 3;
        const float4* src = (const float4*)(x + (size_t)(brow + m) * HID + kq * 32);
        #pragma unroll
        for (int j = 0; j < 8; ++j) {
            float4 v = src[j];
            int k = kq * 32 + j * 4;
            t[m][k] = v.x; t[m][k + 1] = v.y; t[m][k + 2] = v.z; t[m][k + 3] = v.w;
        }
    }
    __syncthreads();

    const int ty = tid >> 4;
    const int tx = tid & 15;
    float c[4][8];

    // ---- layer 1: x -> h ----
    layer_pass(t, As, Bs, bw1, sw1, sc1, tid, c);
    // write h into t (layer_pass ended with a barrier; t reads are done)
    #pragma unroll
    for (int i = 0; i < 4; ++i) {
        int rl = ty * 4 + i;
        *(float4*)&t[rl][tx * 8]     = make_float4(c[i][0], c[i][1], c[i][2], c[i][3]);
        *(float4*)&t[rl][tx * 8 + 4] = make_float4(c[i][4], c[i][5], c[i][6], c[i][7]);
    }
    __syncthreads();

    // ---- layer 2: h -> emb ----
    layer_pass(t, As, Bs, bw2, sw2, sc2, tid, c);
    // write emb to global (output 0) and into t for the assign phase
    #pragma unroll
    for (int i = 0; i < 4; ++i) {
        int rl = ty * 4 + i;
        float4 v0 = make_float4(c[i][0], c[i][1], c[i][2], c[i][3]);
        float4 v1 = make_float4(c[i][4], c[i][5], c[i][6], c[i][7]);
        *(float4*)(emb_out + (size_t)(brow + rl) * HID + tx * 8)     = v0;
        *(float4*)(emb_out + (size_t)(brow + rl) * HID + tx * 8 + 4) = v1;
        *(float4*)&t[rl][tx * 8]     = v0;
        *(float4*)&t[rl][tx * 8 + 4] = v1;
    }
    __syncthreads();

    // ---- cosine-sim argmax. Row norm is a positive per-row scale ->
    //      argmax-invariant, so only proto norms are applied. ----
    const int m  = tid >> 2;   // row 0..63
    const int kq = tid & 3;    // proto sub-partition
    float best = -3.402823466e+38f;
    int   bi   = 0;

    for (int chp = 0; chp < 8; ++chp) {
        // stage 32 protos into Bs[pp][k]
        {
            const int pp  = tid >> 3;   // 0..31
            const int seg = tid & 7;    // 0..7 -> 16 floats each
            const float4* src =
                (const float4*)(protos + (size_t)(chp * 32 + pp) * HID + seg * 16);
            #pragma unroll
            for (int j = 0; j < 4; ++j) {
                float4 v = src[j];
                int k = seg * 16 + j * 4;
                Bs[pp][k] = v.x; Bs[pp][k + 1] = v.y;
                Bs[pp][k + 2] = v.z; Bs[pp][k + 3] = v.w;
            }
        }
        __syncthreads();

        float d[8];
        #pragma unroll
        for (int q = 0; q < 8; ++q) d[q] = 0.0f;
        #pragma unroll
        for (int j = 0; j < 32; ++j) {
            float4 ev = *(const float4*)&t[m][j * 4];
            #pragma unroll
            for (int q = 0; q < 8; ++q) {
                float4 pv = *(const float4*)&Bs[kq * 8 + q][j * 4];
                d[q] = fmaf(ev.x, pv.x, d[q]);
                d[q] = fmaf(ev.y, pv.y, d[q]);
                d[q] = fmaf(ev.z, pv.z, d[q]);
                d[q] = fmaf(ev.w, pv.w, d[q]);
            }
        }
        #pragma unroll
        for (int q = 0; q < 8; ++q) {
            int p = chp * 32 + kq * 8 + q;
            float v = d[q] * rnp[p];
            if (v > best) { best = v; bi = p; }   // ascending p -> first max
        }
        __syncthreads();
    }

    // reduce across the 4 lanes sharing row m (lanes 4m..4m+3)
    #pragma unroll
    for (int off = 1; off < 4; off <<= 1) {
        float ov = __shfl_xor(best, off);
        int   oi = __shfl_xor(bi, off);
        if (ov > best || (ov == best && oi < bi)) { best = ov; bi = oi; }
    }
    if (kq == 0) assign_out[(size_t)brow + m] = (float)bi;
}

// ---------------------------------------------------------------------------
extern "C" void kernel_launch(void* const* d_in, const int* in_sizes, int n_in,
                              void* d_out, int out_size, void* d_ws, size_t ws_size,
                              hipStream_t stream) {
    (void)in_sizes; (void)n_in; (void)out_size; (void)d_ws; (void)ws_size;

    const float* x      = (const float*)d_in[0];
    const float* protos = (const float*)d_in[1];
    // d_in[2] = grid: constants hardcoded (uniform knots (j-3)*0.4 - 1)
    const float* bw1 = (const float*)d_in[3];
    const float* sw1 = (const float*)d_in[4];
    const float* sc1 = (const float*)d_in[5];
    const float* bw2 = (const float*)d_in[6];
    const float* sw2 = (const float*)d_in[7];
    const float* sc2 = (const float*)d_in[8];

    float* out    = (float*)d_out;
    float* embp   = out;                             // (N,128)
    float* assign = out + (size_t)N_ROWS * HID;      // (N,) as float

    kan_fused<<<dim3(N_ROWS / 64), dim3(256), 0, stream>>>(
        x, protos, bw1, sw1, sc1, bw2, sw2, sc2, embp, assign);
}

// Round 4
// 468.712 us; speedup vs baseline: 3.5073x; 3.5073x over previous
//
#include <hip/hip_runtime.h>
#include <math.h>

typedef unsigned short u16;
typedef _Float16 f16;
typedef __attribute__((ext_vector_type(8))) _Float16 f16x8;
typedef __attribute__((ext_vector_type(4))) float f32x4;

#define N_ROWS 131072
#define HID 128
#define WS_CH 8192                    // u16 per packed (layer,chunk) region: [hi|lo][nt][lane][c]
#define N_WCH 72                      // 2 layers * 36 chunks
#define N_PCH 8                       // 2 halves * 4 k-chunks of protos

// ---------------------------------------------------------------------------
// f16 split-2: v ≈ hi + lo with |v - hi - lo| <= 2^-22 |v|  (fp32-grade)
__device__ __forceinline__ void f16_split(float v, f16& hi, f16& lo) {
    f16 h = (f16)v;
    hi = h;
    lo = (f16)(v - (float)h);
}

// cardinal cubic B-spline on uniform knots g[j] = (j-3)*0.4 - 1 -> 8 coef slots
__device__ __forceinline__ void spline8(float xv, float* a8) {
    float s  = (xv + 2.2f) * 2.5f;
    float tf = floorf(s);
    int   tt = (int)tf;
    bool valid = (tt >= 0) && (tt <= 10);
    float kt = (float)(tt - 3) * 0.4f - 1.0f;
    float u  = (xv - kt) * 2.5f;
    float u2 = u * u, u3 = u2 * u;
    float om = 1.0f - u;
    float b3 = u3 * (1.0f / 6.0f);                                   // slot tt
    float b2 = (-3.f * u3 + 3.f * u2 + 3.f * u + 1.f) * (1.0f / 6.0f); // tt-1
    float b1 = (3.f * u3 - 6.f * u2 + 4.f) * (1.0f / 6.0f);          // tt-2
    float b0 = om * om * om * (1.0f / 6.0f);                         // tt-3
    #pragma unroll
    for (int c = 0; c < 8; ++c) {
        int d = tt - c;
        float v = 0.f;
        v = (d == 0) ? b3 : v;
        v = (d == 1) ? b2 : v;
        v = (d == 2) ? b1 : v;
        v = (d == 3) ? b0 : v;
        a8[c] = valid ? v : 0.f;
    }
}

#define GLOAD_LDS16(g, l)                                                         \
    __builtin_amdgcn_global_load_lds(                                             \
        (const __attribute__((address_space(1))) unsigned int*)(g),               \
        (__attribute__((address_space(3))) unsigned int*)(l), 16, 0, 0)

// ---------------------------------------------------------------------------
// Pre-pack: weights (spline_w*scaler folded) and protos -> f16 hi/lo in MFMA
// B-fragment order. ws region r (u16 stride WS_CH):
//   r = l*36 + ch           : layer weights, B[k_local][o]
//   r = 72 + half*4 + kc    : protos,       B[k_local][p_local]
// in-region: idx = (nt*64 + kq*16 + n)*8 + c ; hi at +0, lo at +4096.
// ---------------------------------------------------------------------------
__global__ __launch_bounds__(256)
void pack_weights(const float* __restrict__ bw1, const float* __restrict__ sw1,
                  const float* __restrict__ sc1,
                  const float* __restrict__ bw2, const float* __restrict__ sw2,
                  const float* __restrict__ sc2,
                  const float* __restrict__ protos, u16* __restrict__ ws)
{
    int gid = blockIdx.x * 256 + threadIdx.x;
    if (gid < N_WCH * 4096) {
        int l  = gid / (36 * 4096);
        int r  = gid % (36 * 4096);
        int ch = r / 4096;
        int e  = r % 4096;             // o*32 + k_local
        int o  = e >> 5;
        int kl = e & 31;
        const float* bw = l ? bw2 : bw1;
        const float* sw = l ? sw2 : sw1;
        const float* sc = l ? sc2 : sc1;
        float v;
        if (ch < 4) {
            v = bw[o * HID + ch * 32 + kl];
        } else {
            int i = (ch - 4) * 4 + (kl >> 3);
            v = sw[(o * HID + i) * 8 + (kl & 7)] * sc[o * HID + i];
        }
        f16 hi, lo; f16_split(v, hi, lo);
        int nt = o >> 4, n = o & 15, kq = kl >> 3, c = kl & 7;
        size_t base = (size_t)(l * 36 + ch) * WS_CH;
        size_t idx  = ((size_t)nt * 64 + kq * 16 + n) * 8 + c;
        ws[base + idx]        = __builtin_bit_cast(u16, hi);
        ws[base + 4096 + idx] = __builtin_bit_cast(u16, lo);
    } else if (gid < (N_WCH + N_PCH) * 4096) {
        int r  = gid - N_WCH * 4096;
        int hk = r / 4096;             // half*4 + kc
        int e  = r % 4096;             // p_local*32 + kl
        int pl = e >> 5;
        int kl = e & 31;
        int half = hk >> 2, kc = hk & 3;
        float v = protos[(size_t)(half * 128 + pl) * HID + kc * 32 + kl];
        f16 hi, lo; f16_split(v, hi, lo);
        int nt = pl >> 4, n = pl & 15, kq = kl >> 3, c = kl & 7;
        size_t base = (size_t)(N_WCH + hk) * WS_CH;
        size_t idx  = ((size_t)nt * 64 + kq * 16 + n) * 8 + c;
        ws[base + idx]        = __builtin_bit_cast(u16, hi);
        ws[base + 4096 + idx] = __builtin_bit_cast(u16, lo);
    }
}

// ---------------------------------------------------------------------------
// Fused main kernel: x -> KAN layer1 -> KAN layer2 -> emb -> cosine argmax.
// Per block: 64 rows. Per wave: 16 rows; 16x16x32 f16 MFMA, split hi/lo with
// ALL FOUR products -> relative error ~2^-22 (fp32-grade). d_out write-only.
// ---------------------------------------------------------------------------
__global__ __launch_bounds__(256, 3)
void kan_fused(const float* __restrict__ x, const float* __restrict__ protos,
               const u16* __restrict__ wpack,
               float* __restrict__ emb_out, float* __restrict__ assign_out)
{
    __shared__ float t[64][132];          // x -> h -> emb tile
    __shared__ u16   Bfrag[2][8][64][8];  // [hi/lo][nt][lane(kq*16+n)][c]
    __shared__ float rnp[256];

    const int tid  = threadIdx.x;
    const int lane = tid & 63;
    const int w    = tid >> 6;            // wave 0..3
    const int m    = lane & 15;           // A-row / B-col within 16-tile
    const int q    = lane >> 4;           // 0..3
    const int row  = w * 16 + m;          // row within 64-row block tile
    const int brow = blockIdx.x * 64;

    // ---- proto inverse norms (one proto per thread) ----
    {
        const float4* pr = (const float4*)(protos + (size_t)tid * HID);
        float s = 0.0f;
        #pragma unroll
        for (int j = 0; j < 32; ++j) {
            float4 v = pr[j];
            s += v.x * v.x + v.y * v.y + v.z * v.z + v.w * v.w;
        }
        rnp[tid] = 1.0f / fmaxf(sqrtf(s), 1e-8f);
    }

    // ---- stage x tile ----
    {
        const int m2 = tid >> 2, kq2 = tid & 3;
        const float4* src = (const float4*)(x + (size_t)(brow + m2) * HID + kq2 * 32);
        #pragma unroll
        for (int j = 0; j < 8; ++j) {
            float4 v = src[j];
            int k = kq2 * 32 + j * 4;
            t[m2][k] = v.x; t[m2][k + 1] = v.y; t[m2][k + 2] = v.z; t[m2][k + 3] = v.w;
        }
    }
    __syncthreads();

    union { f16x8 v; f16 h[8]; } ah, al, bh, bl;
    f32x4 acc[8];

    // ================= two KAN layers =================
    for (int l = 0; l < 2; ++l) {
        #pragma unroll
        for (int nt = 0; nt < 8; ++nt) acc[nt] = (f32x4){0.f, 0.f, 0.f, 0.f};

        for (int ch = 0; ch < 36; ++ch) {
            // ---- A fragment in registers ----
            float a8[8];
            if (ch < 4) {
                #pragma unroll
                for (int j = 0; j < 8; ++j) {
                    float xv = t[row][ch * 32 + q * 8 + j];
                    a8[j] = xv / (1.0f + expf(-xv));          // silu
                }
            } else {
                spline8(t[row][(ch - 4) * 4 + q], a8);        // feature i0+q, 8 coefs
            }
            #pragma unroll
            for (int j = 0; j < 8; ++j) f16_split(a8[j], ah.h[j], al.h[j]);

            __syncthreads();   // prior MFMA reads of Bfrag complete
            // ---- async stage packed B fragments (16 KB / chunk) ----
            {
                const char* gsrc = (const char*)(wpack + (size_t)(l * 36 + ch) * WS_CH);
                char* lbase = (char*)&Bfrag[0][0][0][0] + w * 4096;
                #pragma unroll
                for (int i = 0; i < 4; ++i)
                    GLOAD_LDS16(gsrc + w * 4096 + i * 1024 + (size_t)lane * 16,
                                lbase + i * 1024);
            }
            __syncthreads();   // drains vmcnt -> Bfrag ready

            // ---- MFMAs: 8 col-tiles x 4 split products ----
            #pragma unroll
            for (int nt = 0; nt < 8; ++nt) {
                bh.v = *(const f16x8*)Bfrag[0][nt][lane];
                bl.v = *(const f16x8*)Bfrag[1][nt][lane];
                acc[nt] = __builtin_amdgcn_mfma_f32_16x16x32_f16(ah.v, bh.v, acc[nt], 0, 0, 0);
                acc[nt] = __builtin_amdgcn_mfma_f32_16x16x32_f16(ah.v, bl.v, acc[nt], 0, 0, 0);
                acc[nt] = __builtin_amdgcn_mfma_f32_16x16x32_f16(al.v, bh.v, acc[nt], 0, 0, 0);
                acc[nt] = __builtin_amdgcn_mfma_f32_16x16x32_f16(al.v, bl.v, acc[nt], 0, 0, 0);
            }
        }

        // ---- C/D -> t (col = lane&15, row = q*4 + reg) ----
        // safe: all waves passed ch=35 staging barriers => all t reads done
        #pragma unroll
        for (int nt = 0; nt < 8; ++nt)
            #pragma unroll
            for (int r = 0; r < 4; ++r)
                t[w * 16 + q * 4 + r][nt * 16 + m] = acc[nt][r];
        __syncthreads();
    }

    // ---- emb epilogue: coalesced global write from t ----
    {
        const int m2 = tid >> 2, kq2 = tid & 3;
        float* dst = emb_out + (size_t)(brow + m2) * HID + kq2 * 32;
        #pragma unroll
        for (int j = 0; j < 8; ++j)
            *(float4*)(dst + j * 4) = *(const float4*)&t[m2][kq2 * 32 + j * 4];
    }

    // ================= cosine-sim argmax =================
    // row-norm is a positive per-row scale -> argmax-invariant; apply rnp only.
    float best[4]; int bi[4];
    #pragma unroll
    for (int r = 0; r < 4; ++r) { best[r] = -3.402823466e+38f; bi[r] = 0; }

    for (int half = 0; half < 2; ++half) {
        #pragma unroll
        for (int nt = 0; nt < 8; ++nt) acc[nt] = (f32x4){0.f, 0.f, 0.f, 0.f};

        for (int kc = 0; kc < 4; ++kc) {
            float a8[8];
            #pragma unroll
            for (int j = 0; j < 8; ++j) a8[j] = t[row][kc * 32 + q * 8 + j];
            #pragma unroll
            for (int j = 0; j < 8; ++j) f16_split(a8[j], ah.h[j], al.h[j]);

            __syncthreads();
            {
                const char* gsrc =
                    (const char*)(wpack + (size_t)(N_WCH + half * 4 + kc) * WS_CH);
                char* lbase = (char*)&Bfrag[0][0][0][0] + w * 4096;
                #pragma unroll
                for (int i = 0; i < 4; ++i)
                    GLOAD_LDS16(gsrc + w * 4096 + i * 1024 + (size_t)lane * 16,
                                lbase + i * 1024);
            }
            __syncthreads();

            #pragma unroll
            for (int nt = 0; nt < 8; ++nt) {
                bh.v = *(const f16x8*)Bfrag[0][nt][lane];
                bl.v = *(const f16x8*)Bfrag[1][nt][lane];
                acc[nt] = __builtin_amdgcn_mfma_f32_16x16x32_f16(ah.v, bh.v, acc[nt], 0, 0, 0);
                acc[nt] = __builtin_amdgcn_mfma_f32_16x16x32_f16(ah.v, bl.v, acc[nt], 0, 0, 0);
                acc[nt] = __builtin_amdgcn_mfma_f32_16x16x32_f16(al.v, bh.v, acc[nt], 0, 0, 0);
                acc[nt] = __builtin_amdgcn_mfma_f32_16x16x32_f16(al.v, bl.v, acc[nt], 0, 0, 0);
            }
        }

        // ascending p within lane + strict '>' keeps FIRST max (np.argmax)
        #pragma unroll
        for (int nt = 0; nt < 8; ++nt) {
            int p = half * 128 + nt * 16 + m;
            float rp = rnp[p];
            #pragma unroll
            for (int r = 0; r < 4; ++r) {
                float v = acc[nt][r] * rp;
                if (v > best[r]) { best[r] = v; bi[r] = p; }
            }
        }
    }

    // reduce over the 16 lanes (cols) sharing each row; tie -> smaller index
    #pragma unroll
    for (int r = 0; r < 4; ++r) {
        #pragma unroll
        for (int off = 1; off < 16; off <<= 1) {
            float ov = __shfl_xor(best[r], off);
            int   oi = __shfl_xor(bi[r], off);
            if (ov > best[r] || (ov == best[r] && oi < bi[r])) { best[r] = ov; bi[r] = oi; }
        }
        if (m == 0)
            assign_out[(size_t)brow + w * 16 + q * 4 + r] = (float)bi[r];
    }
}

// ---------------------------------------------------------------------------
extern "C" void kernel_launch(void* const* d_in, const int* in_sizes, int n_in,
                              void* d_out, int out_size, void* d_ws, size_t ws_size,
                              hipStream_t stream) {
    (void)in_sizes; (void)n_in; (void)out_size; (void)ws_size;

    const float* x      = (const float*)d_in[0];
    const float* protos = (const float*)d_in[1];
    // d_in[2] = grid: uniform knots (j-3)*0.4 - 1, hardcoded
    const float* bw1 = (const float*)d_in[3];
    const float* sw1 = (const float*)d_in[4];
    const float* sc1 = (const float*)d_in[5];
    const float* bw2 = (const float*)d_in[6];
    const float* sw2 = (const float*)d_in[7];
    const float* sc2 = (const float*)d_in[8];

    float* out    = (float*)d_out;
    float* embp   = out;                             // (N,128)
    float* assign = out + (size_t)N_ROWS * HID;      // (N,) as float
    u16*   wpack  = (u16*)d_ws;                      // 1.31 MB packed fragments

    pack_weights<<<dim3((N_WCH + N_PCH) * 4096 / 256), dim3(256), 0, stream>>>(
        bw1, sw1, sc1, bw2, sw2, sc2, protos, wpack);
    kan_fused<<<dim3(N_ROWS / 64), dim3(256), 0, stream>>>(
        x, protos, wpack, embp, assign);
}